// Round 1
// baseline (299.748 us; speedup 1.0000x reference)
//
#include <hip/hip_runtime.h>
#include <math.h>

#define N_ROWS 8192
#define N_CLS  8192
#define E      64
#define SMOOTH 0.1f

// main kernel tiling
#define RT 32      // rows per block
#define CT 128     // proxies per LDS tile
#define SPLIT 4    // proxy-dimension split across blocks (occupancy)
#define CPB (N_CLS / SPLIT)

// ---------------------------------------------------------------------------
// Kernel 1: L2-normalize (x3) rows of X and proxies; write x_sq/p_sq and
// accumulate sum of p_sq into sumPsq.
// ---------------------------------------------------------------------------
__global__ __launch_bounds__(256) void norm_kernel(
    const float* __restrict__ X, const float* __restrict__ P,
    float* __restrict__ Xn, float* __restrict__ Pn,
    float* __restrict__ x_sq, float* __restrict__ p_sq,
    float* __restrict__ sumPsq)
{
    int row  = blockIdx.x * 4 + (threadIdx.x >> 6);
    int lane = threadIdx.x & 63;
    bool isX = row < N_ROWS;
    int r = isX ? row : row - N_ROWS;
    const float* src = isX ? (X + (size_t)r * E) : (P + (size_t)r * E);
    float v = src[lane];
    float s = v * v;
    #pragma unroll
    for (int off = 32; off; off >>= 1) s += __shfl_xor(s, off);
    float xn = v * (3.0f * rsqrtf(s));
    (isX ? Xn : Pn)[(size_t)r * E + lane] = xn;
    float s2 = xn * xn;
    #pragma unroll
    for (int off = 32; off; off >>= 1) s2 += __shfl_xor(s2, off);
    if (lane == 0) {
        (isX ? x_sq : p_sq)[r] = s2;
        if (!isX) atomicAdd(sumPsq, s2);
    }
}

// ---------------------------------------------------------------------------
// Kernel 2: fused GEMM + row-wise sum(exp(D)) and sum(dot).
// D[i,c] = x_sq[i] + p_sq[c] - 2*dot(Xn_i, Pn_c).  D in (0,36] so exp(D)
// never overflows f32 and no max-subtraction is needed.
// Block: 256 threads, RT=32 rows x CT=128-proxy LDS tiles, 4x4 micro-tile.
// Grid: (N_ROWS/RT, SPLIT); each block handles CPB proxies, atomically
// accumulating per-row partials.
// LDS tiles stored transposed [e][r]/[e][c] with XOR swizzle ((e&7)<<2) to
// keep ds_read_b128 conflict-free and staging writes at 8-way.
// ---------------------------------------------------------------------------
__global__ __launch_bounds__(256) void main_kernel(
    const float* __restrict__ Xn, const float* __restrict__ Pn,
    const float* __restrict__ x_sq, const float* __restrict__ p_sq,
    float* __restrict__ rowSumExp, float* __restrict__ rowSumDot)
{
    __shared__ __align__(16) float aT[E][RT];   // 8 KB
    __shared__ __align__(16) float bT[E][CT];   // 32 KB
    __shared__ float psq_s[CT];

    const int tid = threadIdx.x;
    const int r0  = blockIdx.x * RT;
    const int cs  = blockIdx.y * CPB;

    // stage A transposed + swizzled (once)
    {
        int rr = tid >> 6;         // 0..3
        int e  = tid & 63;
        int swz = (e & 7) << 2;
        #pragma unroll
        for (int i = 0; i < RT; i += 4) {
            int r = i + rr;
            aT[e][r ^ swz] = Xn[(size_t)(r0 + r) * E + e];
        }
    }

    const int rg = tid >> 5;   // 0..7 : rows r0 + rg*4 + {0..3}
    const int cg = tid & 31;   // 0..31: cols  base + cg*4 + {0..3}

    float xsq_r[4];
    #pragma unroll
    for (int i = 0; i < 4; ++i) xsq_r[i] = x_sq[r0 + rg * 4 + i];

    float accE[4] = {0.f, 0.f, 0.f, 0.f};
    float accD[4] = {0.f, 0.f, 0.f, 0.f};

    for (int t = 0; t < CPB / CT; ++t) {
        const int cb = cs + t * CT;
        __syncthreads();   // protect bT from previous iteration's readers
        // stage B tile: CT x E floats = 2048 float4, 8 per thread
        #pragma unroll
        for (int i = 0; i < 8; ++i) {
            int f  = i * 256 + tid;        // 0..2047
            int c  = f >> 4;               // 0..127
            int e4 = (f & 15) << 2;        // 0,4,...,60
            const float4 v = *reinterpret_cast<const float4*>(
                &Pn[(size_t)(cb + c) * E + e4]);
            bT[e4 + 0][c ^ (((e4 + 0) & 7) << 2)] = v.x;
            bT[e4 + 1][c ^ (((e4 + 1) & 7) << 2)] = v.y;
            bT[e4 + 2][c ^ (((e4 + 2) & 7) << 2)] = v.z;
            bT[e4 + 3][c ^ (((e4 + 3) & 7) << 2)] = v.w;
        }
        if (tid < CT) psq_s[tid] = p_sq[cb + tid];
        __syncthreads();

        float dot[4][4] = {};
        #pragma unroll
        for (int e = 0; e < E; ++e) {
            const int swz = (e & 7) << 2;
            const float4 a = *reinterpret_cast<const float4*>(&aT[e][(rg * 4) ^ swz]);
            const float4 b = *reinterpret_cast<const float4*>(&bT[e][(cg * 4) ^ swz]);
            dot[0][0] = fmaf(a.x, b.x, dot[0][0]);
            dot[0][1] = fmaf(a.x, b.y, dot[0][1]);
            dot[0][2] = fmaf(a.x, b.z, dot[0][2]);
            dot[0][3] = fmaf(a.x, b.w, dot[0][3]);
            dot[1][0] = fmaf(a.y, b.x, dot[1][0]);
            dot[1][1] = fmaf(a.y, b.y, dot[1][1]);
            dot[1][2] = fmaf(a.y, b.z, dot[1][2]);
            dot[1][3] = fmaf(a.y, b.w, dot[1][3]);
            dot[2][0] = fmaf(a.z, b.x, dot[2][0]);
            dot[2][1] = fmaf(a.z, b.y, dot[2][1]);
            dot[2][2] = fmaf(a.z, b.z, dot[2][2]);
            dot[2][3] = fmaf(a.z, b.w, dot[2][3]);
            dot[3][0] = fmaf(a.w, b.x, dot[3][0]);
            dot[3][1] = fmaf(a.w, b.y, dot[3][1]);
            dot[3][2] = fmaf(a.w, b.z, dot[3][2]);
            dot[3][3] = fmaf(a.w, b.w, dot[3][3]);
        }

        #pragma unroll
        for (int ri = 0; ri < 4; ++ri) {
            #pragma unroll
            for (int ci = 0; ci < 4; ++ci) {
                float d = xsq_r[ri] + psq_s[cg * 4 + ci] - 2.0f * dot[ri][ci];
                accE[ri] += __expf(d);
                accD[ri] += dot[ri][ci];
            }
        }
    }

    // reduce across the 32 cg lanes (same rows)
    #pragma unroll
    for (int ri = 0; ri < 4; ++ri) {
        #pragma unroll
        for (int off = 16; off; off >>= 1) {
            accE[ri] += __shfl_xor(accE[ri], off);
            accD[ri] += __shfl_xor(accD[ri], off);
        }
    }
    if (cg == 0) {
        #pragma unroll
        for (int ri = 0; ri < 4; ++ri) {
            atomicAdd(&rowSumExp[r0 + rg * 4 + ri], accE[ri]);
            atomicAdd(&rowSumDot[r0 + rg * 4 + ri], accD[ri]);
        }
    }
}

// ---------------------------------------------------------------------------
// Kernel 3: per-row finalize.
// term_i = log(sumExp_i) - (0.9*Dt_i + (0.1/8191)*(sumD_i - Dt_i))
// sumD_i = C*x_sq_i + sumPsq - 2*sumDot_i ;  Dt_i needs one gathered dot.
// loss = mean(term). One wave per row, 16 rows per block, one atomic/block.
// ---------------------------------------------------------------------------
__global__ __launch_bounds__(1024) void final_kernel(
    const float* __restrict__ Xn, const float* __restrict__ Pn,
    const int* __restrict__ T,
    const float* __restrict__ x_sq, const float* __restrict__ p_sq,
    const float* __restrict__ rowSumExp, const float* __restrict__ rowSumDot,
    const float* __restrict__ sumPsq, float* __restrict__ out)
{
    __shared__ float terms[16];
    int wid  = threadIdx.x >> 6;
    int lane = threadIdx.x & 63;
    int row  = blockIdx.x * 16 + wid;
    int t    = T[row];
    float xn = Xn[(size_t)row * E + lane];
    float pt = Pn[(size_t)t * E + lane];
    float d  = xn * pt;
    #pragma unroll
    for (int off = 32; off; off >>= 1) d += __shfl_xor(d, off);
    if (lane == 0) {
        float Dt   = x_sq[row] + p_sq[t] - 2.0f * d;
        float sumD = (float)N_CLS * x_sq[row] + sumPsq[0] - 2.0f * rowSumDot[row];
        float lse  = __logf(rowSumExp[row]);
        float term = lse - ((1.0f - SMOOTH) * Dt
                            + (SMOOTH / (float)(N_CLS - 1)) * (sumD - Dt));
        terms[wid] = term;
    }
    __syncthreads();
    if (threadIdx.x == 0) {
        float s = 0.f;
        #pragma unroll
        for (int i = 0; i < 16; ++i) s += terms[i];
        atomicAdd(out, s * (1.0f / (float)N_ROWS));
    }
}

// ---------------------------------------------------------------------------
extern "C" void kernel_launch(void* const* d_in, const int* in_sizes, int n_in,
                              void* d_out, int out_size, void* d_ws, size_t ws_size,
                              hipStream_t stream)
{
    const float* X = (const float*)d_in[0];
    const int*   T = (const int*)d_in[1];
    const float* P = (const float*)d_in[2];

    float* ws        = (float*)d_ws;
    float* Xn        = ws;                       // 8192*64
    float* Pn        = Xn + (size_t)N_ROWS * E;  // 8192*64
    float* x_sq      = Pn + (size_t)N_CLS * E;   // 8192
    float* p_sq      = x_sq + N_ROWS;            // 8192
    float* rowSumExp = p_sq + N_CLS;             // 8192
    float* rowSumDot = rowSumExp + N_ROWS;       // 8192
    float* sumPsq    = rowSumDot + N_ROWS;       // 1
    float* out       = (float*)d_out;

    // zero the accumulated buffers (rowSumExp, rowSumDot, sumPsq contiguous)
    hipMemsetAsync(rowSumExp, 0, (size_t)(2 * N_ROWS + 1) * sizeof(float), stream);
    hipMemsetAsync(out, 0, sizeof(float), stream);

    norm_kernel<<<(N_ROWS + N_CLS) / 4, 256, 0, stream>>>(
        X, P, Xn, Pn, x_sq, p_sq, sumPsq);

    dim3 grid(N_ROWS / RT, SPLIT);
    main_kernel<<<grid, 256, 0, stream>>>(Xn, Pn, x_sq, p_sq, rowSumExp, rowSumDot);

    final_kernel<<<N_ROWS / 16, 1024, 0, stream>>>(
        Xn, Pn, T, x_sq, p_sq, rowSumExp, rowSumDot, sumPsq, out);
}

// Round 2
// 55.323 us; speedup vs baseline: 5.4181x; 5.4181x over previous
//
#include <hip/hip_runtime.h>
#include <math.h>

#define NR 8192
#define NC 8192
#define EE 64
#define LOG2E 1.4426950408889634f

typedef __attribute__((ext_vector_type(8))) short bf16x8;   // 8 bf16 = 4 VGPR
typedef __attribute__((ext_vector_type(4))) float f32x4;

__device__ __forceinline__ float bf2f(unsigned short u) {
    unsigned int x = ((unsigned int)u) << 16;
    return __builtin_bit_cast(float, x);
}
__device__ __forceinline__ unsigned short f2bf(float f) {
    unsigned int u = __builtin_bit_cast(unsigned int, f);
    u += 0x7FFFu + ((u >> 16) & 1u);
    return (unsigned short)(u >> 16);
}

// ---------------------------------------------------------------------------
// Kernel 1: L2-normalize (x3) rows of X and proxies -> bf16.
// ||out_row||^2 == 9 exactly, so no x_sq/p_sq needed anywhere.
// ---------------------------------------------------------------------------
__global__ __launch_bounds__(256) void norm_kernel(
    const float* __restrict__ X, const float* __restrict__ P,
    unsigned short* __restrict__ Xb, unsigned short* __restrict__ Pb)
{
    int row  = blockIdx.x * 4 + (threadIdx.x >> 6);
    int lane = threadIdx.x & 63;
    bool isX = row < NR;
    int r = isX ? row : row - NR;
    const float* src = isX ? X : P;
    float v = src[(size_t)r * EE + lane];
    float s = v * v;
    #pragma unroll
    for (int off = 32; off; off >>= 1) s += __shfl_xor(s, off);
    float xn = v * (3.0f * rsqrtf(s));
    (isX ? Xb : Pb)[(size_t)r * EE + lane] = f2bf(xn);
}

// ---------------------------------------------------------------------------
// Kernel 2: sumPn[e] = sum over all proxies of Pn[c][e]  (64 floats).
// Lets final_kernel get rowSumDot_i = dot(x_i, sumPn) for free.
// ---------------------------------------------------------------------------
__global__ __launch_bounds__(256) void colsum_kernel(
    const unsigned short* __restrict__ Pb, float* __restrict__ sumPn)
{
    int w = threadIdx.x >> 6, l = threadIdx.x & 63;
    float acc = 0.f;
    int rbase = blockIdx.x * 128 + w * 32;
    for (int i = 0; i < 32; ++i)
        acc += bf2f(Pb[(size_t)(rbase + i) * EE + l]);
    __shared__ float red[4][64];
    red[w][l] = acc;
    __syncthreads();
    if (w == 0)
        atomicAdd(&sumPn[l], red[0][l] + red[1][l] + red[2][l] + red[3][l]);
}

// ---------------------------------------------------------------------------
// Kernel 3: MFMA GEMM + exp epilogue.
// rowSumExp[i] = sum_c exp(18 - 2*dot(x_i, p_c))   (no max-sub needed: D<=36)
// Block = 4 waves; each wave owns the SAME 64 rows (A frags in registers for
// the whole kernel) and a disjoint set of 16-col tiles. No LDS. B fragments
// stream from L2 (Pn = 1 MB, fully resident).
// Grid: (8192/64 row panels, 16 col splits).
// ---------------------------------------------------------------------------
__global__ __launch_bounds__(256) void main_kernel(
    const unsigned short* __restrict__ Xb, const unsigned short* __restrict__ Pb,
    float* __restrict__ rowSumExp)
{
    const int tid = threadIdx.x;
    const int w  = tid >> 6, l = tid & 63;
    const int lr = l & 15, lg = l >> 4;
    const int r0 = blockIdx.x * 64;
    const int cbase = blockIdx.y * 512;

    // A fragments: rows r0 + rt*16 + lr, k = kk*32 + lg*8 .. +8
    bf16x8 a[4][2];
    #pragma unroll
    for (int rt = 0; rt < 4; ++rt)
        #pragma unroll
        for (int kk = 0; kk < 2; ++kk)
            a[rt][kk] = *reinterpret_cast<const bf16x8*>(
                Xb + (size_t)(r0 + rt * 16 + lr) * EE + kk * 32 + lg * 8);

    float accE[4][4] = {};
    const float KN  = -2.0f * LOG2E;
    const float C18 = 18.0f * LOG2E;

    #pragma unroll 2
    for (int j = 0; j < 8; ++j) {
        const int c0 = cbase + (j * 4 + w) * 16;
        const size_t bb = (size_t)(c0 + lr) * EE + lg * 8;
        bf16x8 b0 = *reinterpret_cast<const bf16x8*>(Pb + bb);
        bf16x8 b1 = *reinterpret_cast<const bf16x8*>(Pb + bb + 32);
        #pragma unroll
        for (int rt = 0; rt < 4; ++rt) {
            f32x4 d = {0.f, 0.f, 0.f, 0.f};
            d = __builtin_amdgcn_mfma_f32_16x16x32_bf16(a[rt][0], b0, d, 0, 0, 0);
            d = __builtin_amdgcn_mfma_f32_16x16x32_bf16(a[rt][1], b1, d, 0, 0, 0);
            // C/D layout: col = lane&15, row = (lane>>4)*4 + q  [m89/m91 verified]
            #pragma unroll
            for (int q = 0; q < 4; ++q)
                accE[rt][q] += __builtin_exp2f(fmaf(KN, d[q], C18));
        }
    }

    // sum over the 16 cols held by lanes sharing lg (xor bits 0..3)
    #pragma unroll
    for (int rt = 0; rt < 4; ++rt)
        #pragma unroll
        for (int q = 0; q < 4; ++q) {
            float v = accE[rt][q];
            v += __shfl_xor(v, 1);
            v += __shfl_xor(v, 2);
            v += __shfl_xor(v, 4);
            v += __shfl_xor(v, 8);
            if (lr == 0)
                atomicAdd(&rowSumExp[r0 + rt * 16 + lg * 4 + q], v);
        }
}

// ---------------------------------------------------------------------------
// Kernel 4: finalize.
// term_i = log(sumExp_i) - [0.9*Dt_i + (0.1/8191)*(sumD_i - Dt_i)]
//   Dt_i   = 18 - 2*dot(x_i, p_{T_i})
//   sumD_i = 8192*18 - 2*dot(x_i, sumPn)
// loss = mean(term).  64 rows/block -> 128 blocks -> 128 atomics on out.
// ---------------------------------------------------------------------------
__global__ __launch_bounds__(1024) void final_kernel(
    const unsigned short* __restrict__ Xb, const unsigned short* __restrict__ Pb,
    const int* __restrict__ T, const float* __restrict__ sumPn,
    const float* __restrict__ rowSumExp, float* __restrict__ out)
{
    __shared__ float terms[16];
    int wid = threadIdx.x >> 6, lane = threadIdx.x & 63;
    float sp = sumPn[lane];
    float wsum = 0.f;
    #pragma unroll
    for (int rr = 0; rr < 4; ++rr) {
        int row = blockIdx.x * 64 + wid * 4 + rr;
        int t = T[row];
        float x  = bf2f(Xb[(size_t)row * EE + lane]);
        float pt = bf2f(Pb[(size_t)t  * EE + lane]);
        float d1 = x * pt;
        float d2 = x * sp;
        #pragma unroll
        for (int off = 32; off; off >>= 1) {
            d1 += __shfl_xor(d1, off);
            d2 += __shfl_xor(d2, off);
        }
        if (lane == 0) {
            float Dt   = 18.0f - 2.0f * d1;
            float sumD = (float)NC * 18.0f - 2.0f * d2;
            float lse  = __logf(rowSumExp[row]);
            wsum += lse - (0.9f * Dt + (0.1f / 8191.0f) * (sumD - Dt));
        }
    }
    if (lane == 0) terms[wid] = wsum;
    __syncthreads();
    if (threadIdx.x == 0) {
        float s = 0.f;
        #pragma unroll
        for (int i = 0; i < 16; ++i) s += terms[i];
        atomicAdd(out, s * (1.0f / (float)NR));
    }
}

// ---------------------------------------------------------------------------
extern "C" void kernel_launch(void* const* d_in, const int* in_sizes, int n_in,
                              void* d_out, int out_size, void* d_ws, size_t ws_size,
                              hipStream_t stream)
{
    const float* X = (const float*)d_in[0];
    const int*   T = (const int*)d_in[1];
    const float* P = (const float*)d_in[2];

    unsigned short* Xb = (unsigned short*)d_ws;
    unsigned short* Pb = Xb + (size_t)NR * EE;
    float* rowSumExp = (float*)(Pb + (size_t)NC * EE);
    float* sumPn     = rowSumExp + NR;
    float* out       = (float*)d_out;

    hipMemsetAsync(rowSumExp, 0, (size_t)(NR + 64) * sizeof(float), stream);
    hipMemsetAsync(out, 0, sizeof(float), stream);

    norm_kernel<<<(NR + NC) / 4, 256, 0, stream>>>(X, P, Xb, Pb);
    colsum_kernel<<<64, 256, 0, stream>>>(Pb, sumPn);
    main_kernel<<<dim3(NR / 64, 16), 256, 0, stream>>>(Xb, Pb, rowSumExp);
    final_kernel<<<NR / 64, 1024, 0, stream>>>(Xb, Pb, T, sumPn, rowSumExp, out);
}

// Round 3
// 47.964 us; speedup vs baseline: 6.2495x; 1.1534x over previous
//
#include <hip/hip_runtime.h>
#include <math.h>

#define NR 8192
#define NC 8192
#define EE 64
#define LOG2E   1.4426950408889634f
#define KSCALE  (-2.0f * LOG2E)        // folded into Xs
#define C18     (18.0f * LOG2E)        // folded into MFMA C-init
#define NSPLIT  32                     // col splits in main
#define CPS     (NC / NSPLIT)          // 256 cols per split

typedef __attribute__((ext_vector_type(8))) short bf16x8;
typedef __attribute__((ext_vector_type(4))) float f32x4;

__device__ __forceinline__ float bf2f(unsigned short u) {
    unsigned int x = ((unsigned int)u) << 16;
    return __builtin_bit_cast(float, x);
}
__device__ __forceinline__ unsigned short f2bf(float f) {
    unsigned int u = __builtin_bit_cast(unsigned int, f);
    u += 0x7FFFu + ((u >> 16) & 1u);
    return (unsigned short)(u >> 16);
}

// ---------------------------------------------------------------------------
// K1: L2-normalize (x3) rows of X and proxies -> bf16.
// X rows additionally write Xs = Xn * (-2*log2e)  (scale folded for main).
// ||row||^2 == 9 exactly, so no x_sq/p_sq needed anywhere.
// ---------------------------------------------------------------------------
__global__ __launch_bounds__(256) void norm_kernel(
    const float* __restrict__ X, const float* __restrict__ P,
    unsigned short* __restrict__ Xb, unsigned short* __restrict__ Xs,
    unsigned short* __restrict__ Pb)
{
    int row  = blockIdx.x * 4 + (threadIdx.x >> 6);
    int lane = threadIdx.x & 63;
    bool isX = row < NR;
    int r = isX ? row : row - NR;
    const float* src = isX ? X : P;
    float v = src[(size_t)r * EE + lane];
    float s = v * v;
    #pragma unroll
    for (int off = 32; off; off >>= 1) s += __shfl_xor(s, off);
    float xn = v * (3.0f * rsqrtf(s));
    if (isX) {
        Xb[(size_t)r * EE + lane] = f2bf(xn);
        Xs[(size_t)r * EE + lane] = f2bf(xn * KSCALE);
    } else {
        Pb[(size_t)r * EE + lane] = f2bf(xn);
    }
}

// ---------------------------------------------------------------------------
// K2: column-sum partials of Pb. Block b sums its 128 rows -> part[b][e].
// No atomics, no init needed (pure overwrite).
// ---------------------------------------------------------------------------
__global__ __launch_bounds__(256) void colsum_kernel(
    const unsigned short* __restrict__ Pb, float* __restrict__ sumPnPart)
{
    int w = threadIdx.x >> 6, l = threadIdx.x & 63;
    float acc = 0.f;
    int rbase = blockIdx.x * 128 + w * 32;
    for (int i = 0; i < 32; ++i)
        acc += bf2f(Pb[(size_t)(rbase + i) * EE + l]);
    __shared__ float red[4][64];
    red[w][l] = acc;
    __syncthreads();
    if (w == 0)
        sumPnPart[blockIdx.x * 64 + l] =
            red[0][l] + red[1][l] + red[2][l] + red[3][l];
}

// ---------------------------------------------------------------------------
// K3: MFMA GEMM + exp epilogue.
// d = mfma(Xs, Pn, C18) = log2e*(18 - 2*dot)  ->  accE += exp2(d).
// Block = 4 waves; wave w owns rows r0+w*64..+64 (A frags in regs); all
// waves iterate the SAME 256-col slice -> B fragments shared via L1.
// Writes per-split partials ePart[row][NSPLIT] (no atomics, no init).
// Grid: (32 row panels, 32 col splits) = 1024 blocks.
// ---------------------------------------------------------------------------
__global__ __launch_bounds__(256) void main_kernel(
    const unsigned short* __restrict__ Xs, const unsigned short* __restrict__ Pb,
    float* __restrict__ ePart)
{
    const int tid = threadIdx.x;
    const int w  = tid >> 6, l = tid & 63;
    const int lr = l & 15, lg = l >> 4;
    const int r0 = blockIdx.x * 256 + w * 64;
    const int cbase = blockIdx.y * CPS;
    const int s = blockIdx.y;

    bf16x8 a[4][2];
    #pragma unroll
    for (int rt = 0; rt < 4; ++rt)
        #pragma unroll
        for (int kk = 0; kk < 2; ++kk)
            a[rt][kk] = *reinterpret_cast<const bf16x8*>(
                Xs + (size_t)(r0 + rt * 16 + lr) * EE + kk * 32 + lg * 8);

    float accE[4][4] = {};
    const f32x4 dinit = {C18, C18, C18, C18};

    #pragma unroll 2
    for (int j = 0; j < CPS / 16; ++j) {
        const int c0 = cbase + j * 16;
        const size_t bb = (size_t)(c0 + lr) * EE + lg * 8;
        bf16x8 b0 = *reinterpret_cast<const bf16x8*>(Pb + bb);
        bf16x8 b1 = *reinterpret_cast<const bf16x8*>(Pb + bb + 32);
        #pragma unroll
        for (int rt = 0; rt < 4; ++rt) {
            f32x4 d = dinit;
            d = __builtin_amdgcn_mfma_f32_16x16x32_bf16(a[rt][0], b0, d, 0, 0, 0);
            d = __builtin_amdgcn_mfma_f32_16x16x32_bf16(a[rt][1], b1, d, 0, 0, 0);
            // D layout: col = lane&15, row = (lane>>4)*4 + q
            #pragma unroll
            for (int q = 0; q < 4; ++q)
                accE[rt][q] += __builtin_exp2f(d[q]);
        }
    }

    #pragma unroll
    for (int rt = 0; rt < 4; ++rt)
        #pragma unroll
        for (int q = 0; q < 4; ++q) {
            float v = accE[rt][q];
            v += __shfl_xor(v, 1);
            v += __shfl_xor(v, 2);
            v += __shfl_xor(v, 4);
            v += __shfl_xor(v, 8);
            if (lr == 0)
                ePart[(size_t)(r0 + rt * 16 + lg * 4 + q) * NSPLIT + s] = v;
        }
}

// ---------------------------------------------------------------------------
// K4: per-row finalize -> per-block loss partials.
// term_i = log(sumExp_i) - [0.9*Dt_i + (0.1/8191)*(sumD_i - Dt_i)]
//   Dt_i   = 18 - 2*dot(x_i, p_{T_i})
//   sumD_i = 8192*18 - 2*dot(x_i, sumPn)
// 64 rows/block, 16 waves; writes lossPart[block].
// ---------------------------------------------------------------------------
__global__ __launch_bounds__(1024) void final_kernel(
    const unsigned short* __restrict__ Xb, const unsigned short* __restrict__ Pb,
    const int* __restrict__ T, const float* __restrict__ sumPnPart,
    const float* __restrict__ ePart, float* __restrict__ lossPart)
{
    __shared__ float spn[64];
    __shared__ float terms[16];
    int wid = threadIdx.x >> 6, lane = threadIdx.x & 63;

    if (threadIdx.x < 64) {
        float s = 0.f;
        for (int b = 0; b < 64; ++b) s += sumPnPart[b * 64 + threadIdx.x];
        spn[threadIdx.x] = s;
    }
    __syncthreads();

    float sp = spn[lane];
    float wsum = 0.f;
    #pragma unroll
    for (int rr = 0; rr < 4; ++rr) {
        int row = blockIdx.x * 64 + wid * 4 + rr;
        int t = T[row];
        float x  = bf2f(Xb[(size_t)row * EE + lane]);
        float pt = bf2f(Pb[(size_t)t  * EE + lane]);
        float d1 = x * pt;
        float d2 = x * sp;
        float es = (lane < NSPLIT) ? ePart[(size_t)row * NSPLIT + lane] : 0.f;
        #pragma unroll
        for (int off = 32; off; off >>= 1) {
            d1 += __shfl_xor(d1, off);
            d2 += __shfl_xor(d2, off);
            es += __shfl_xor(es, off);
        }
        if (lane == 0) {
            float Dt   = 18.0f - 2.0f * d1;
            float sumD = (float)NC * 18.0f - 2.0f * d2;
            float lse  = __logf(es);
            wsum += lse - (0.9f * Dt + (0.1f / 8191.0f) * (sumD - Dt));
        }
    }
    if (lane == 0) terms[wid] = wsum;
    __syncthreads();
    if (threadIdx.x == 0) {
        float s = 0.f;
        #pragma unroll
        for (int i = 0; i < 16; ++i) s += terms[i];
        lossPart[blockIdx.x] = s;
    }
}

// ---------------------------------------------------------------------------
// K5: reduce 128 loss partials -> out (overwrite, no init needed).
// ---------------------------------------------------------------------------
__global__ __launch_bounds__(128) void reduce_kernel(
    const float* __restrict__ lossPart, float* __restrict__ out)
{
    __shared__ float red[2];
    int w = threadIdx.x >> 6, l = threadIdx.x & 63;
    float v = lossPart[threadIdx.x];
    #pragma unroll
    for (int off = 32; off; off >>= 1) v += __shfl_xor(v, off);
    if (l == 0) red[w] = v;
    __syncthreads();
    if (threadIdx.x == 0)
        out[0] = (red[0] + red[1]) * (1.0f / (float)NR);
}

// ---------------------------------------------------------------------------
extern "C" void kernel_launch(void* const* d_in, const int* in_sizes, int n_in,
                              void* d_out, int out_size, void* d_ws, size_t ws_size,
                              hipStream_t stream)
{
    const float* X = (const float*)d_in[0];
    const int*   T = (const int*)d_in[1];
    const float* P = (const float*)d_in[2];

    unsigned short* Xb = (unsigned short*)d_ws;                 // 1 MB
    unsigned short* Xs = Xb + (size_t)NR * EE;                  // 1 MB
    unsigned short* Pb = Xs + (size_t)NR * EE;                  // 1 MB
    float* ePart     = (float*)(Pb + (size_t)NC * EE);          // 1 MB
    float* sumPnPart = ePart + (size_t)NR * NSPLIT;             // 16 KB
    float* lossPart  = sumPnPart + 64 * 64;                     // 512 B
    float* out       = (float*)d_out;

    norm_kernel<<<(NR + NC) / 4, 256, 0, stream>>>(X, P, Xb, Xs, Pb);
    colsum_kernel<<<64, 256, 0, stream>>>(Pb, sumPnPart);
    main_kernel<<<dim3(NR / 256, NSPLIT), 256, 0, stream>>>(Xs, Pb, ePart);
    final_kernel<<<NR / 64, 1024, 0, stream>>>(Xb, Pb, T, sumPnPart, ePart, lossPart);
    reduce_kernel<<<1, 128, 0, stream>>>(lossPart, out);
}